// Round 1
// baseline (2781.549 us; speedup 1.0000x reference)
//
#include <hip/hip_runtime.h>
#include <hip/hip_bf16.h>
#include <cmath>

// GEMM: Y[n][o] = sum_k x[n][k] * W[o][k] + b[o]
// W staged transposed in LDS (Wt[k][o], pad 130) -> conflict-free float2 reads.
// Each wave: 4 rows x (2 cols/lane) register tile.
__global__ __launch_bounds__(256) void gemm_bias_kernel(
    const float* __restrict__ x, const float* __restrict__ W,
    const float* __restrict__ b, float* __restrict__ Y, int N)
{
    __shared__ float Wt[128][130];
    __shared__ float xr[4][4][128];
    const int tid  = threadIdx.x;
    const int wave = tid >> 6;
    const int lane = tid & 63;

    for (int i = tid; i < 128 * 128; i += 256) {
        const int o = i >> 7, k = i & 127;
        Wt[k][o] = W[i];
    }
    __syncthreads();

    const float2 bv = *(const float2*)&b[2 * lane];

    const int ngroups = N >> 2;  // N divisible by 4 (100000)
    for (int g = blockIdx.x * 4 + wave; g < ngroups; g += gridDim.x * 4) {
        const int row0 = g << 2;
#pragma unroll
        for (int rr = 0; rr < 4; ++rr) {
            *(float2*)&xr[wave][rr][2 * lane] =
                *(const float2*)&x[(size_t)(row0 + rr) * 128 + 2 * lane];
        }
        float acc[4][2] = {};
#pragma unroll 4
        for (int k = 0; k < 128; ++k) {
            const float2 w = *(const float2*)&Wt[k][2 * lane];
#pragma unroll
            for (int rr = 0; rr < 4; ++rr) {
                const float xv = xr[wave][rr][k];
                acc[rr][0] = fmaf(xv, w.x, acc[rr][0]);
                acc[rr][1] = fmaf(xv, w.y, acc[rr][1]);
            }
        }
#pragma unroll
        for (int rr = 0; rr < 4; ++rr) {
            float2 o2;
            o2.x = acc[rr][0] + bv.x;
            o2.y = acc[rr][1] + bv.y;
            *(float2*)&Y[(size_t)(row0 + rr) * 128 + 2 * lane] = o2;
        }
    }
}

// One wave per edge: lanes cover 128 cols as float2; 2 fp32 atomics per lane.
__global__ __launch_bounds__(256) void scatter_kernel(
    const int* __restrict__ rows, const int* __restrict__ cols,
    const float* __restrict__ vals, const float* __restrict__ Y,
    float* __restrict__ out, int E)
{
    const long long gid = (long long)blockIdx.x * blockDim.x + threadIdx.x;
    const int wid  = (int)(gid >> 6);
    const int lane = threadIdx.x & 63;
    if (wid >= E) return;
    const int   r = rows[wid];
    const int   c = cols[wid];
    const float v = vals[wid];
    const float2 y = *(const float2*)&Y[(size_t)c * 128 + 2 * lane];
    float* po = &out[(size_t)r * 128 + 2 * lane];
    atomicAdd(po,     v * y.x);
    atomicAdd(po + 1, v * y.y);
}

__global__ __launch_bounds__(256) void elu_kernel(float* __restrict__ out, int n4)
{
    int i = blockIdx.x * blockDim.x + threadIdx.x;
    const int stride = gridDim.x * blockDim.x;
    float4* p = (float4*)out;
    for (; i < n4; i += stride) {
        float4 v = p[i];
        v.x = v.x > 0.f ? v.x : expf(v.x) - 1.f;
        v.y = v.y > 0.f ? v.y : expf(v.y) - 1.f;
        v.z = v.z > 0.f ? v.z : expf(v.z) - 1.f;
        v.w = v.w > 0.f ? v.w : expf(v.w) - 1.f;
        p[i] = v;
    }
}

extern "C" void kernel_launch(void* const* d_in, const int* in_sizes, int n_in,
                              void* d_out, int out_size, void* d_ws, size_t ws_size,
                              hipStream_t stream)
{
    const float* x    = (const float*)d_in[0];
    const float* W    = (const float*)d_in[1];
    const float* b    = (const float*)d_in[2];
    const int*   rows = (const int*)d_in[3];
    const int*   cols = (const int*)d_in[4];
    const float* vals = (const float*)d_in[5];
    float* out = (float*)d_out;
    float* Y   = (float*)d_ws;   // N*128 fp32 = 51.2 MB scratch

    const int N = in_sizes[0] / 128;
    const int E = in_sizes[3];

    // Harness poisons d_out with 0xAA before every timed launch -> zero it.
    hipMemsetAsync(d_out, 0, (size_t)out_size * sizeof(float), stream);

    gemm_bias_kernel<<<512, 256, 0, stream>>>(x, W, b, Y, N);

    const int nwaves  = E;                 // one wave per edge
    const int nblocks = (nwaves + 3) / 4;  // 4 waves per 256-thread block
    scatter_kernel<<<nblocks, 256, 0, stream>>>(rows, cols, vals, Y, out, E);

    elu_kernel<<<1024, 256, 0, stream>>>(out, out_size / 4);
}

// Round 2
// 1000.523 us; speedup vs baseline: 2.7801x; 2.7801x over previous
//
#include <hip/hip_runtime.h>
#include <hip/hip_bf16.h>
#include <cmath>

// ---------------- GEMM: Y[n][o] = sum_k x[n][k] * W[o][k] + b[o] -------------
__global__ __launch_bounds__(256) void gemm_bias_kernel(
    const float* __restrict__ x, const float* __restrict__ W,
    const float* __restrict__ b, float* __restrict__ Y, int N)
{
    __shared__ float Wt[128][130];
    __shared__ float xr[4][4][128];
    const int tid  = threadIdx.x;
    const int wave = tid >> 6;
    const int lane = tid & 63;

    for (int i = tid; i < 128 * 128; i += 256) {
        const int o = i >> 7, k = i & 127;
        Wt[k][o] = W[i];
    }
    __syncthreads();

    const float2 bv = *(const float2*)&b[2 * lane];

    const int ngroups = N >> 2;  // N divisible by 4 (100000)
    for (int g = blockIdx.x * 4 + wave; g < ngroups; g += gridDim.x * 4) {
        const int row0 = g << 2;
#pragma unroll
        for (int rr = 0; rr < 4; ++rr) {
            *(float2*)&xr[wave][rr][2 * lane] =
                *(const float2*)&x[(size_t)(row0 + rr) * 128 + 2 * lane];
        }
        float acc[4][2] = {};
#pragma unroll 4
        for (int k = 0; k < 128; ++k) {
            const float2 w = *(const float2*)&Wt[k][2 * lane];
#pragma unroll
            for (int rr = 0; rr < 4; ++rr) {
                const float xv = xr[wave][rr][k];
                acc[rr][0] = fmaf(xv, w.x, acc[rr][0]);
                acc[rr][1] = fmaf(xv, w.y, acc[rr][1]);
            }
        }
#pragma unroll
        for (int rr = 0; rr < 4; ++rr) {
            float2 o2;
            o2.x = acc[rr][0] + bv.x;
            o2.y = acc[rr][1] + bv.y;
            *(float2*)&Y[(size_t)(row0 + rr) * 128 + 2 * lane] = o2;
        }
    }
}

// ---------------- CSR build: histogram -> scan -> reorder --------------------
__global__ __launch_bounds__(256) void hist_kernel(
    const int* __restrict__ rows, int* __restrict__ cnt, int E)
{
    const int i = blockIdx.x * blockDim.x + threadIdx.x;
    if (i < E) atomicAdd(&cnt[rows[i]], 1);
}

// Exclusive scan of cnt[0..N) into row_start[0..N]; also re-init cursor=row_start.
// NOTE: cnt and cursor may alias (same buffer) — per-thread read-then-write on
// its own chunk only, which is safe.
__global__ __launch_bounds__(1024) void scan_kernel(
    const int* __restrict__ cnt, int* __restrict__ row_start,
    int* __restrict__ cursor, int N, int E)
{
    __shared__ int sums[1024];
    const int t  = threadIdx.x;
    const int CH = (N + 1023) >> 10;
    const int lo = t * CH;
    const int hi = min(lo + CH, N);

    int s = 0;
    for (int i = lo; i < hi; ++i) s += cnt[i];
    sums[t] = s;
    __syncthreads();
    // Hillis-Steele inclusive scan over 1024 partials
    for (int off = 1; off < 1024; off <<= 1) {
        int v = (t >= off) ? sums[t - off] : 0;
        __syncthreads();
        sums[t] += v;
        __syncthreads();
    }
    int run = (t > 0) ? sums[t - 1] : 0;
    for (int i = lo; i < hi; ++i) {
        const int c = cnt[i];
        row_start[i] = run;
        cursor[i]    = run;
        run += c;
    }
    if (t == 0) row_start[N] = E;
}

__global__ __launch_bounds__(256) void reorder_kernel(
    const int* __restrict__ rows, const int* __restrict__ cols,
    const float* __restrict__ vals, int* __restrict__ cursor,
    int2* __restrict__ pairs, int E)
{
    const int i = blockIdx.x * blockDim.x + threadIdx.x;
    if (i < E) {
        const int r   = rows[i];
        const int pos = atomicAdd(&cursor[r], 1);
        pairs[pos] = make_int2(cols[i], __float_as_int(vals[i]));
    }
}

// ---------------- Gather + segment-sum + ELU (one wave per row) --------------
__global__ __launch_bounds__(256) void gather_rows_kernel(
    const int2* __restrict__ pairs, const int* __restrict__ row_start,
    const float* __restrict__ Y, float* __restrict__ out, int N)
{
    const int wid  = (blockIdx.x * blockDim.x + threadIdx.x) >> 6;
    const int lane = threadIdx.x & 63;
    if (wid >= N) return;
    const int s = row_start[wid];
    const int e = row_start[wid + 1];

    float2 acc = make_float2(0.f, 0.f);
    int j = s;
    for (; j + 2 <= e; j += 2) {
        const int2 p0 = pairs[j];
        const int2 p1 = pairs[j + 1];
        const float2 y0 = *(const float2*)&Y[(size_t)p0.x * 128 + 2 * lane];
        const float2 y1 = *(const float2*)&Y[(size_t)p1.x * 128 + 2 * lane];
        const float v0 = __int_as_float(p0.y);
        const float v1 = __int_as_float(p1.y);
        acc.x = fmaf(v0, y0.x, acc.x);
        acc.y = fmaf(v0, y0.y, acc.y);
        acc.x = fmaf(v1, y1.x, acc.x);
        acc.y = fmaf(v1, y1.y, acc.y);
    }
    if (j < e) {
        const int2 p = pairs[j];
        const float2 y = *(const float2*)&Y[(size_t)p.x * 128 + 2 * lane];
        const float v = __int_as_float(p.y);
        acc.x = fmaf(v, y.x, acc.x);
        acc.y = fmaf(v, y.y, acc.y);
    }
    float2 o;
    o.x = acc.x > 0.f ? acc.x : expf(acc.x) - 1.f;
    o.y = acc.y > 0.f ? acc.y : expf(acc.y) - 1.f;
    *(float2*)&out[(size_t)wid * 128 + 2 * lane] = o;
}

// ---------------- Fallback path (R1): atomic scatter -------------------------
__global__ __launch_bounds__(256) void scatter_kernel(
    const int* __restrict__ rows, const int* __restrict__ cols,
    const float* __restrict__ vals, const float* __restrict__ Y,
    float* __restrict__ out, int E)
{
    const long long gid = (long long)blockIdx.x * blockDim.x + threadIdx.x;
    const int wid  = (int)(gid >> 6);
    const int lane = threadIdx.x & 63;
    if (wid >= E) return;
    const int   r = rows[wid];
    const int   c = cols[wid];
    const float v = vals[wid];
    const float2 y = *(const float2*)&Y[(size_t)c * 128 + 2 * lane];
    float* po = &out[(size_t)r * 128 + 2 * lane];
    atomicAdd(po,     v * y.x);
    atomicAdd(po + 1, v * y.y);
}

__global__ __launch_bounds__(256) void elu_kernel(float* __restrict__ out, int n4)
{
    int i = blockIdx.x * blockDim.x + threadIdx.x;
    const int stride = gridDim.x * blockDim.x;
    float4* p = (float4*)out;
    for (; i < n4; i += stride) {
        float4 v = p[i];
        v.x = v.x > 0.f ? v.x : expf(v.x) - 1.f;
        v.y = v.y > 0.f ? v.y : expf(v.y) - 1.f;
        v.z = v.z > 0.f ? v.z : expf(v.z) - 1.f;
        v.w = v.w > 0.f ? v.w : expf(v.w) - 1.f;
        p[i] = v;
    }
}

// -----------------------------------------------------------------------------
extern "C" void kernel_launch(void* const* d_in, const int* in_sizes, int n_in,
                              void* d_out, int out_size, void* d_ws, size_t ws_size,
                              hipStream_t stream)
{
    const float* x    = (const float*)d_in[0];
    const float* W    = (const float*)d_in[1];
    const float* b    = (const float*)d_in[2];
    const int*   rows = (const int*)d_in[3];
    const int*   cols = (const int*)d_in[4];
    const float* vals = (const float*)d_in[5];
    float* out = (float*)d_out;

    const int N = in_sizes[0] / 128;
    const int E = in_sizes[3];

    // Workspace layout (256 B aligned)
    auto align256 = [](size_t v) { return (v + 255) & ~(size_t)255; };
    const size_t offY      = 0;
    const size_t offPairs  = align256(offY + (size_t)N * 128 * 4);
    const size_t offStart  = align256(offPairs + (size_t)E * 8);
    const size_t offCursor = align256(offStart + ((size_t)N + 1) * 4);
    const size_t need      = offCursor + (size_t)N * 4;

    float* Y = (float*)((char*)d_ws + offY);

    gemm_bias_kernel<<<512, 256, 0, stream>>>(x, W, b, Y, N);

    if (need <= ws_size) {
        int2* pairs     = (int2*)((char*)d_ws + offPairs);
        int*  row_start = (int*)((char*)d_ws + offStart);
        int*  cursor    = (int*)((char*)d_ws + offCursor);

        hipMemsetAsync(cursor, 0, (size_t)N * 4, stream);
        hist_kernel<<<(E + 255) / 256, 256, 0, stream>>>(rows, cursor, E);
        scan_kernel<<<1, 1024, 0, stream>>>(cursor, row_start, cursor, N, E);
        reorder_kernel<<<(E + 255) / 256, 256, 0, stream>>>(rows, cols, vals,
                                                            cursor, pairs, E);
        const int nblocks = (N + 3) / 4;  // 4 waves (rows) per 256-thread block
        gather_rows_kernel<<<nblocks, 256, 0, stream>>>(pairs, row_start, Y, out, N);
    } else {
        // Fallback: R1 atomic-scatter path
        hipMemsetAsync(d_out, 0, (size_t)out_size * sizeof(float), stream);
        const int nblocks = (E + 3) / 4;
        scatter_kernel<<<nblocks, 256, 0, stream>>>(rows, cols, vals, Y, out, E);
        elu_kernel<<<1024, 256, 0, stream>>>(out, out_size / 4);
    }
}

// Round 3
// 722.887 us; speedup vs baseline: 3.8478x; 1.3841x over previous
//
#include <hip/hip_runtime.h>
#include <hip/hip_bf16.h>
#include <cmath>

#define RPB 32      // rows per bucket (N=100000 = 3125*32 exactly)
#define CAP 2048    // max edges per bucket in LDS sort (avg 1024, ~30 sigma)
#define NBLK 2048   // blocks for hist/append passes (shard = blockIdx & 7)

// ---------------- GEMM: Y[n][o] = sum_k x[n][k] * W[o][k] + b[o] -------------
__global__ __launch_bounds__(256) void gemm_bias_kernel(
    const float* __restrict__ x, const float* __restrict__ W,
    const float* __restrict__ b, float* __restrict__ Y, int N)
{
    __shared__ float Wt[128][130];
    __shared__ float xr[4][4][128];
    const int tid  = threadIdx.x;
    const int wave = tid >> 6;
    const int lane = tid & 63;

    for (int i = tid; i < 128 * 128; i += 256) {
        const int o = i >> 7, k = i & 127;
        Wt[k][o] = W[i];
    }
    __syncthreads();

    const float2 bv = *(const float2*)&b[2 * lane];

    const int ngroups = N >> 2;
    for (int g = blockIdx.x * 4 + wave; g < ngroups; g += gridDim.x * 4) {
        const int row0 = g << 2;
#pragma unroll
        for (int rr = 0; rr < 4; ++rr) {
            *(float2*)&xr[wave][rr][2 * lane] =
                *(const float2*)&x[(size_t)(row0 + rr) * 128 + 2 * lane];
        }
        float acc[4][2] = {};
#pragma unroll 4
        for (int k = 0; k < 128; ++k) {
            const float2 w = *(const float2*)&Wt[k][2 * lane];
#pragma unroll
            for (int rr = 0; rr < 4; ++rr) {
                const float xv = xr[wave][rr][k];
                acc[rr][0] = fmaf(xv, w.x, acc[rr][0]);
                acc[rr][1] = fmaf(xv, w.y, acc[rr][1]);
            }
        }
#pragma unroll
        for (int rr = 0; rr < 4; ++rr) {
            float2 o2;
            o2.x = acc[rr][0] + bv.x;
            o2.y = acc[rr][1] + bv.y;
            *(float2*)&Y[(size_t)(row0 + rr) * 128 + 2 * lane] = o2;
        }
    }
}

// ---------------- P1: per-bucket x per-shard histogram -----------------------
__global__ __launch_bounds__(256) void hist_kernel(
    const int* __restrict__ rows, int* __restrict__ counts, int NB, int E)
{
    __shared__ int h[3136];
    const int t = threadIdx.x;
    for (int i = t; i < NB; i += 256) h[i] = 0;
    __syncthreads();
    const int chunk = (E + NBLK - 1) / NBLK;
    const int lo = blockIdx.x * chunk;
    const int hi = min(lo + chunk, E);
    for (int i = lo + t; i < hi; i += 256)
        atomicAdd(&h[rows[i] >> 5], 1);
    __syncthreads();
    const int s = blockIdx.x & 7;
    for (int i = t; i < NB; i += 256) {
        const int c = h[i];
        if (c) atomicAdd(&counts[i * 8 + s], c);
    }
}

// ---------------- P2: exclusive scan over NB*8 counters ----------------------
__global__ __launch_bounds__(1024) void scan_kernel(
    const int* __restrict__ counts, int* __restrict__ base,
    int* __restrict__ cursor, int M, int E)
{
    __shared__ int sums[1024];
    const int t  = threadIdx.x;
    const int CH = (M + 1023) >> 10;
    const int lo = t * CH;
    const int hi = min(lo + CH, M);

    int s = 0;
    for (int i = lo; i < hi; ++i) s += counts[i];
    sums[t] = s;
    __syncthreads();
    for (int off = 1; off < 1024; off <<= 1) {
        int v = (t >= off) ? sums[t - off] : 0;
        __syncthreads();
        sums[t] += v;
        __syncthreads();
    }
    int run = (t > 0) ? sums[t - 1] : 0;
    for (int i = lo; i < hi; ++i) {
        const int c = counts[i];
        base[i]   = run;
        cursor[i] = run;
        run += c;
    }
    if (t == 0) base[M] = E;
}

// ---------------- P3: append edges to bucket/shard streams -------------------
__global__ __launch_bounds__(256) void bucket_scatter_kernel(
    const int* __restrict__ rows, const int* __restrict__ cols,
    const float* __restrict__ vals, int* __restrict__ cursor,
    int2* __restrict__ pairs, int E)
{
    const int t = threadIdx.x;
    const int chunk = (E + NBLK - 1) / NBLK;
    const int lo = blockIdx.x * chunk;
    const int hi = min(lo + chunk, E);
    const int s = blockIdx.x & 7;
    for (int i = lo + t; i < hi; i += 256) {
        const int r   = rows[i];
        const int pos = atomicAdd(&cursor[(r >> 5) * 8 + s], 1);
        pairs[pos] = make_int2(((r & 31) << 17) | cols[i], __float_as_int(vals[i]));
    }
}

// ---------------- P4: per-bucket counting sort in LDS (in place) -------------
__global__ __launch_bounds__(256) void bucket_sort_kernel(
    const int* __restrict__ base, int2* __restrict__ pairs,
    int* __restrict__ row_start, int NB, int N, int E)
{
    __shared__ int2 sbuf[CAP];
    __shared__ int2 dbuf[CAP];
    __shared__ int hist[RPB];
    __shared__ int off[RPB];
    __shared__ int cur[RPB];
    const int b  = blockIdx.x;
    const int t  = threadIdx.x;
    const int s0 = base[b * 8];
    const int e0 = (b + 1 < NB) ? base[(b + 1) * 8] : E;
    const int cnt = e0 - s0;

    if (t < RPB) hist[t] = 0;
    __syncthreads();
    for (int i = t; i < cnt; i += 256) {
        const int2 p = pairs[s0 + i];
        sbuf[i] = p;
        atomicAdd(&hist[p.x >> 17], 1);
    }
    __syncthreads();
    if (t == 0) {
        int run = 0;
#pragma unroll
        for (int k = 0; k < RPB; ++k) { off[k] = run; cur[k] = run; run += hist[k]; }
    }
    __syncthreads();
    const int r0 = b * RPB;
    if (t < RPB && r0 + t < N) row_start[r0 + t] = s0 + off[t];
    if (b == 0 && t == 0) row_start[N] = E;
    for (int i = t; i < cnt; i += 256) {
        const int2 p   = sbuf[i];
        const int  pos = atomicAdd(&cur[p.x >> 17], 1);
        dbuf[pos] = make_int2(p.x & 0x1FFFF, p.y);
    }
    __syncthreads();
    for (int i = t; i < cnt; i += 256) pairs[s0 + i] = dbuf[i];
}

// ---------------- P5: gather + segment-sum + fused ELU (wave per row) --------
__global__ __launch_bounds__(256) void gather_rows_kernel(
    const int2* __restrict__ pairs, const int* __restrict__ row_start,
    const float* __restrict__ Y, float* __restrict__ out, int N)
{
    const int wid  = (blockIdx.x * blockDim.x + threadIdx.x) >> 6;
    const int lane = threadIdx.x & 63;
    if (wid >= N) return;
    const int s = row_start[wid];
    const int e = row_start[wid + 1];

    float2 acc = make_float2(0.f, 0.f);
    int j = s;
    for (; j + 4 <= e; j += 4) {
        const int2 p0 = pairs[j];
        const int2 p1 = pairs[j + 1];
        const int2 p2 = pairs[j + 2];
        const int2 p3 = pairs[j + 3];
        const float2 y0 = *(const float2*)&Y[(size_t)p0.x * 128 + 2 * lane];
        const float2 y1 = *(const float2*)&Y[(size_t)p1.x * 128 + 2 * lane];
        const float2 y2 = *(const float2*)&Y[(size_t)p2.x * 128 + 2 * lane];
        const float2 y3 = *(const float2*)&Y[(size_t)p3.x * 128 + 2 * lane];
        acc.x = fmaf(__int_as_float(p0.y), y0.x, acc.x);
        acc.y = fmaf(__int_as_float(p0.y), y0.y, acc.y);
        acc.x = fmaf(__int_as_float(p1.y), y1.x, acc.x);
        acc.y = fmaf(__int_as_float(p1.y), y1.y, acc.y);
        acc.x = fmaf(__int_as_float(p2.y), y2.x, acc.x);
        acc.y = fmaf(__int_as_float(p2.y), y2.y, acc.y);
        acc.x = fmaf(__int_as_float(p3.y), y3.x, acc.x);
        acc.y = fmaf(__int_as_float(p3.y), y3.y, acc.y);
    }
    for (; j < e; ++j) {
        const int2 p = pairs[j];
        const float2 y = *(const float2*)&Y[(size_t)p.x * 128 + 2 * lane];
        const float v = __int_as_float(p.y);
        acc.x = fmaf(v, y.x, acc.x);
        acc.y = fmaf(v, y.y, acc.y);
    }
    float2 o;
    o.x = acc.x > 0.f ? acc.x : expf(acc.x) - 1.f;
    o.y = acc.y > 0.f ? acc.y : expf(acc.y) - 1.f;
    *(float2*)&out[(size_t)wid * 128 + 2 * lane] = o;
}

// ---------------- Fallback path (R1): atomic scatter -------------------------
__global__ __launch_bounds__(256) void scatter_kernel(
    const int* __restrict__ rows, const int* __restrict__ cols,
    const float* __restrict__ vals, const float* __restrict__ Y,
    float* __restrict__ out, int E)
{
    const long long gid = (long long)blockIdx.x * blockDim.x + threadIdx.x;
    const int wid  = (int)(gid >> 6);
    const int lane = threadIdx.x & 63;
    if (wid >= E) return;
    const int   r = rows[wid];
    const int   c = cols[wid];
    const float v = vals[wid];
    const float2 y = *(const float2*)&Y[(size_t)c * 128 + 2 * lane];
    float* po = &out[(size_t)r * 128 + 2 * lane];
    atomicAdd(po,     v * y.x);
    atomicAdd(po + 1, v * y.y);
}

__global__ __launch_bounds__(256) void elu_kernel(float* __restrict__ out, int n4)
{
    int i = blockIdx.x * blockDim.x + threadIdx.x;
    const int stride = gridDim.x * blockDim.x;
    float4* p = (float4*)out;
    for (; i < n4; i += stride) {
        float4 v = p[i];
        v.x = v.x > 0.f ? v.x : expf(v.x) - 1.f;
        v.y = v.y > 0.f ? v.y : expf(v.y) - 1.f;
        v.z = v.z > 0.f ? v.z : expf(v.z) - 1.f;
        v.w = v.w > 0.f ? v.w : expf(v.w) - 1.f;
        p[i] = v;
    }
}

// -----------------------------------------------------------------------------
extern "C" void kernel_launch(void* const* d_in, const int* in_sizes, int n_in,
                              void* d_out, int out_size, void* d_ws, size_t ws_size,
                              hipStream_t stream)
{
    const float* x    = (const float*)d_in[0];
    const float* W    = (const float*)d_in[1];
    const float* b    = (const float*)d_in[2];
    const int*   rows = (const int*)d_in[3];
    const int*   cols = (const int*)d_in[4];
    const float* vals = (const float*)d_in[5];
    float* out = (float*)d_out;

    const int N  = in_sizes[0] / 128;
    const int E  = in_sizes[3];
    const int NB = (N + RPB - 1) / RPB;
    const int M  = NB * 8;

    auto align256 = [](size_t v) { return (v + 255) & ~(size_t)255; };
    const size_t offY      = 0;
    const size_t offPairs  = align256(offY + (size_t)N * 128 * 4);
    const size_t offCounts = align256(offPairs + (size_t)E * 8);
    const size_t offBase   = align256(offCounts + (size_t)M * 4);
    const size_t offCursor = align256(offBase + ((size_t)M + 1) * 4);
    const size_t offStart  = align256(offCursor + (size_t)M * 4);
    const size_t need      = offStart + ((size_t)N + 1) * 4;

    float* Y = (float*)((char*)d_ws + offY);

    gemm_bias_kernel<<<512, 256, 0, stream>>>(x, W, b, Y, N);

    if (need <= ws_size && NB <= 3136 && N < (1 << 17)) {
        int2* pairs     = (int2*)((char*)d_ws + offPairs);
        int*  counts    = (int*)((char*)d_ws + offCounts);
        int*  base      = (int*)((char*)d_ws + offBase);
        int*  cursor    = (int*)((char*)d_ws + offCursor);
        int*  row_start = (int*)((char*)d_ws + offStart);

        hipMemsetAsync(counts, 0, (size_t)M * 4, stream);
        hist_kernel<<<NBLK, 256, 0, stream>>>(rows, counts, NB, E);
        scan_kernel<<<1, 1024, 0, stream>>>(counts, base, cursor, M, E);
        bucket_scatter_kernel<<<NBLK, 256, 0, stream>>>(rows, cols, vals,
                                                        cursor, pairs, E);
        bucket_sort_kernel<<<NB, 256, 0, stream>>>(base, pairs, row_start,
                                                   NB, N, E);
        const int nblocks = (N + 3) / 4;
        gather_rows_kernel<<<nblocks, 256, 0, stream>>>(pairs, row_start, Y, out, N);
    } else {
        hipMemsetAsync(d_out, 0, (size_t)out_size * sizeof(float), stream);
        const int nblocks = (E + 3) / 4;
        scatter_kernel<<<nblocks, 256, 0, stream>>>(rows, cols, vals, Y, out, E);
        elu_kernel<<<1024, 256, 0, stream>>>(out, out_size / 4);
    }
}

// Round 4
// 442.763 us; speedup vs baseline: 6.2822x; 1.6327x over previous
//
#include <hip/hip_runtime.h>
#include <hip/hip_bf16.h>
#include <cmath>

#define RPB  32     // rows per bucket
#define SCAP 240    // per-shard capacity per bucket (mean 128, +9.9 sigma)
#define BCAP (8 * SCAP)  // 1920: bucket slot capacity
#define NBLK 2048   // blocks for scatter pass (shard = blockIdx & 7)

typedef __attribute__((ext_vector_type(8))) short short8;
typedef __attribute__((ext_vector_type(4))) float floatx4;

__device__ __forceinline__ unsigned short f2bf(float f) {
    unsigned int u = __float_as_uint(f);
    u += 0x7FFFu + ((u >> 16) & 1u);   // RNE
    return (unsigned short)(u >> 16);
}

// ---------------- MFMA GEMM: Yb[n][o] = bf16( x@W^T + b ) --------------------
// Block = 256 thr = 4 waves, handles 64 rows. Wave w: rows [base+16w, +16).
// A-frag: A[m=lane&15][k=quad*8+j]; B-frag: B[k=quad*8+j][n=lane&15] with
// B[k][n]=W[n][k] -> read W row-major. C/D: col=lane&15, row=quad*4+reg.
__global__ __launch_bounds__(256) void gemm_mfma_kernel(
    const float* __restrict__ x, const float* __restrict__ W,
    const float* __restrict__ b, unsigned short* __restrict__ Yb, int N)
{
    __shared__ unsigned short Wb[128][136];  // [o][k], pad 136 (2-way free)
    __shared__ unsigned short Xb[64][136];   // [row][k]
    const int t    = threadIdx.x;
    const int wave = t >> 6;
    const int lane = t & 63;
    const int col  = lane & 15;
    const int quad = lane >> 4;
    const int rowbase = blockIdx.x * 64;

    // Stage W (128x128 fp32 -> bf16), 16 float4 per thread.
#pragma unroll
    for (int i = 0; i < 16; ++i) {
        const int idx = t + 256 * i;        // float4 index
        const int o = idx >> 5, k4 = (idx & 31) * 4;
        const float4 v = *(const float4*)&W[(size_t)idx * 4];
        Wb[o][k4 + 0] = f2bf(v.x); Wb[o][k4 + 1] = f2bf(v.y);
        Wb[o][k4 + 2] = f2bf(v.z); Wb[o][k4 + 3] = f2bf(v.w);
    }
    // Stage 64 rows of x, 8 float4 per thread.
#pragma unroll
    for (int i = 0; i < 8; ++i) {
        const int idx = t + 256 * i;
        const int row = idx >> 5, k4 = (idx & 31) * 4;
        const int gr = rowbase + row;
        float4 v = make_float4(0.f, 0.f, 0.f, 0.f);
        if (gr < N) v = *(const float4*)&x[(size_t)gr * 128 + k4];
        Xb[row][k4 + 0] = f2bf(v.x); Xb[row][k4 + 1] = f2bf(v.y);
        Xb[row][k4 + 2] = f2bf(v.z); Xb[row][k4 + 3] = f2bf(v.w);
    }
    __syncthreads();

    float bias[8];
#pragma unroll
    for (int nt = 0; nt < 8; ++nt) bias[nt] = b[nt * 16 + col];

    floatx4 acc[8] = {};
    const int mrow = wave * 16;
#pragma unroll
    for (int k0 = 0; k0 < 128; k0 += 32) {
        const short8 a = *(const short8*)&Xb[mrow + col][k0 + quad * 8];
#pragma unroll
        for (int nt = 0; nt < 8; ++nt) {
            const short8 bf = *(const short8*)&Wb[nt * 16 + col][k0 + quad * 8];
            acc[nt] = __builtin_amdgcn_mfma_f32_16x16x32_bf16(a, bf, acc[nt], 0, 0, 0);
        }
    }
#pragma unroll
    for (int nt = 0; nt < 8; ++nt) {
#pragma unroll
        for (int reg = 0; reg < 4; ++reg) {
            const int gr = rowbase + mrow + quad * 4 + reg;
            if (gr < N)
                Yb[(size_t)gr * 128 + nt * 16 + col] = f2bf(acc[nt][reg] + bias[nt]);
        }
    }
}

// ---------------- P1: init bucket/shard cursors to fixed slot bases ----------
__global__ __launch_bounds__(256) void init_cursor_kernel(int* __restrict__ cursor, int M)
{
    const int i = blockIdx.x * blockDim.x + threadIdx.x;
    if (i < M) cursor[i] = (i >> 3) * BCAP + (i & 7) * SCAP;
}

// ---------------- P2: append edges to fixed-cap bucket/shard streams ---------
__global__ __launch_bounds__(256) void bucket_scatter_kernel(
    const int* __restrict__ rows, const int* __restrict__ cols,
    const float* __restrict__ vals, int* __restrict__ cursor,
    int2* __restrict__ pairs, int E)
{
    const int t = threadIdx.x;
    const int chunk = (E + NBLK - 1) / NBLK;
    const int lo = blockIdx.x * chunk;
    const int hi = min(lo + chunk, E);
    const int s = blockIdx.x & 7;
    for (int i = lo + t; i < hi; i += 256) {
        const int r   = rows[i];
        const int pos = atomicAdd(&cursor[(r >> 5) * 8 + s], 1);
        pairs[pos] = make_int2(((r & 31) << 17) | cols[i], __float_as_int(vals[i]));
    }
}

// ---------------- P3: per-bucket compact + counting sort in LDS --------------
__global__ __launch_bounds__(256) void bucket_sort_kernel(
    const int* __restrict__ cursor, int2* __restrict__ pairs,
    int2* __restrict__ row_se, int NB, int N)
{
    __shared__ int2 sbuf[BCAP];
    __shared__ int2 dbuf[BCAP];
    __shared__ int hist[RPB];
    __shared__ int off[RPB];
    __shared__ int cur[RPB];
    __shared__ int segoff[9];
    const int b    = blockIdx.x;
    const int t    = threadIdx.x;
    const int slot = b * BCAP;

    if (t < RPB) hist[t] = 0;
    if (t == 0) {
        int run = 0;
#pragma unroll
        for (int s = 0; s < 8; ++s) {
            segoff[s] = run;
            run += cursor[b * 8 + s] - (slot + s * SCAP);
        }
        segoff[8] = run;
    }
    __syncthreads();
    const int cnt = segoff[8];
    for (int s = 0; s < 8; ++s) {
        const int so = segoff[s];
        const int c  = segoff[s + 1] - so;
        for (int i = t; i < c; i += 256) {
            const int2 p = pairs[slot + s * SCAP + i];
            sbuf[so + i] = p;
            atomicAdd(&hist[p.x >> 17], 1);
        }
    }
    __syncthreads();
    if (t == 0) {
        int run = 0;
#pragma unroll
        for (int k = 0; k < RPB; ++k) { off[k] = run; cur[k] = run; run += hist[k]; }
    }
    __syncthreads();
    const int r0 = b * RPB;
    if (t < RPB && r0 + t < N)
        row_se[r0 + t] = make_int2(slot + off[t], slot + off[t] + hist[t]);
    for (int i = t; i < cnt; i += 256) {
        const int2 p   = sbuf[i];
        const int  pos = atomicAdd(&cur[p.x >> 17], 1);
        dbuf[pos] = make_int2(p.x & 0x1FFFF, p.y);
    }
    __syncthreads();
    for (int i = t; i < cnt; i += 256) pairs[slot + i] = dbuf[i];
}

// ---------------- P4: gather(bf16 Y) + segment-sum + fused ELU ---------------
__global__ __launch_bounds__(256) void gather_rows_kernel(
    const int2* __restrict__ pairs, const int2* __restrict__ row_se,
    const unsigned int* __restrict__ Yu,   // bf16 Y viewed as uint (2 elems)
    float* __restrict__ out, int N)
{
    const int wid  = (blockIdx.x * blockDim.x + threadIdx.x) >> 6;
    const int lane = threadIdx.x & 63;
    if (wid >= N) return;
    const int2 se = row_se[wid];
    const int s = se.x, e = se.y;

    float2 acc = make_float2(0.f, 0.f);
    int j = s;
    for (; j + 4 <= e; j += 4) {
        const int2 p0 = pairs[j];
        const int2 p1 = pairs[j + 1];
        const int2 p2 = pairs[j + 2];
        const int2 p3 = pairs[j + 3];
        const unsigned int y0 = Yu[(size_t)p0.x * 64 + lane];
        const unsigned int y1 = Yu[(size_t)p1.x * 64 + lane];
        const unsigned int y2 = Yu[(size_t)p2.x * 64 + lane];
        const unsigned int y3 = Yu[(size_t)p3.x * 64 + lane];
        const float v0 = __int_as_float(p0.y), v1 = __int_as_float(p1.y);
        const float v2 = __int_as_float(p2.y), v3 = __int_as_float(p3.y);
        acc.x = fmaf(v0, __uint_as_float(y0 << 16), acc.x);
        acc.y = fmaf(v0, __uint_as_float(y0 & 0xFFFF0000u), acc.y);
        acc.x = fmaf(v1, __uint_as_float(y1 << 16), acc.x);
        acc.y = fmaf(v1, __uint_as_float(y1 & 0xFFFF0000u), acc.y);
        acc.x = fmaf(v2, __uint_as_float(y2 << 16), acc.x);
        acc.y = fmaf(v2, __uint_as_float(y2 & 0xFFFF0000u), acc.y);
        acc.x = fmaf(v3, __uint_as_float(y3 << 16), acc.x);
        acc.y = fmaf(v3, __uint_as_float(y3 & 0xFFFF0000u), acc.y);
    }
    for (; j < e; ++j) {
        const int2 p = pairs[j];
        const unsigned int y = Yu[(size_t)p.x * 64 + lane];
        const float v = __int_as_float(p.y);
        acc.x = fmaf(v, __uint_as_float(y << 16), acc.x);
        acc.y = fmaf(v, __uint_as_float(y & 0xFFFF0000u), acc.y);
    }
    float2 o;
    o.x = acc.x > 0.f ? acc.x : expf(acc.x) - 1.f;
    o.y = acc.y > 0.f ? acc.y : expf(acc.y) - 1.f;
    *(float2*)&out[(size_t)wid * 128 + 2 * lane] = o;
}

// ---------------- Fallback path (fp32, atomic scatter) -----------------------
__global__ __launch_bounds__(256) void gemm_bias_kernel(
    const float* __restrict__ x, const float* __restrict__ W,
    const float* __restrict__ b, float* __restrict__ Y, int N)
{
    __shared__ float Wt[128][130];
    const int tid  = threadIdx.x;
    const int wave = tid >> 6;
    const int lane = tid & 63;
    for (int i = tid; i < 128 * 128; i += 256) {
        const int o = i >> 7, k = i & 127;
        Wt[k][o] = W[i];
    }
    __syncthreads();
    const float2 bv = *(const float2*)&b[2 * lane];
    for (int row = blockIdx.x * 4 + wave; row < N; row += gridDim.x * 4) {
        float acc0 = 0.f, acc1 = 0.f;
        for (int k = 0; k < 128; ++k) {
            const float2 w = *(const float2*)&Wt[k][2 * lane];
            const float xv = x[(size_t)row * 128 + k];
            acc0 = fmaf(xv, w.x, acc0);
            acc1 = fmaf(xv, w.y, acc1);
        }
        float2 o2; o2.x = acc0 + bv.x; o2.y = acc1 + bv.y;
        *(float2*)&Y[(size_t)row * 128 + 2 * lane] = o2;
    }
}

__global__ __launch_bounds__(256) void scatter_kernel(
    const int* __restrict__ rows, const int* __restrict__ cols,
    const float* __restrict__ vals, const float* __restrict__ Y,
    float* __restrict__ out, int E)
{
    const long long gid = (long long)blockIdx.x * blockDim.x + threadIdx.x;
    const int wid  = (int)(gid >> 6);
    const int lane = threadIdx.x & 63;
    if (wid >= E) return;
    const int   r = rows[wid];
    const int   c = cols[wid];
    const float v = vals[wid];
    const float2 y = *(const float2*)&Y[(size_t)c * 128 + 2 * lane];
    float* po = &out[(size_t)r * 128 + 2 * lane];
    atomicAdd(po,     v * y.x);
    atomicAdd(po + 1, v * y.y);
}

__global__ __launch_bounds__(256) void elu_kernel(float* __restrict__ out, int n4)
{
    int i = blockIdx.x * blockDim.x + threadIdx.x;
    const int stride = gridDim.x * blockDim.x;
    float4* p = (float4*)out;
    for (; i < n4; i += stride) {
        float4 v = p[i];
        v.x = v.x > 0.f ? v.x : expf(v.x) - 1.f;
        v.y = v.y > 0.f ? v.y : expf(v.y) - 1.f;
        v.z = v.z > 0.f ? v.z : expf(v.z) - 1.f;
        v.w = v.w > 0.f ? v.w : expf(v.w) - 1.f;
        p[i] = v;
    }
}

// -----------------------------------------------------------------------------
extern "C" void kernel_launch(void* const* d_in, const int* in_sizes, int n_in,
                              void* d_out, int out_size, void* d_ws, size_t ws_size,
                              hipStream_t stream)
{
    const float* x    = (const float*)d_in[0];
    const float* W    = (const float*)d_in[1];
    const float* b    = (const float*)d_in[2];
    const int*   rows = (const int*)d_in[3];
    const int*   cols = (const int*)d_in[4];
    const float* vals = (const float*)d_in[5];
    float* out = (float*)d_out;

    const int N  = in_sizes[0] / 128;
    const int E  = in_sizes[3];
    const int NB = (N + RPB - 1) / RPB;
    const int M  = NB * 8;

    auto align256 = [](size_t v) { return (v + 255) & ~(size_t)255; };
    const size_t offY      = 0;                                   // bf16 Y
    const size_t offPairs  = align256(offY + (size_t)N * 128 * 2);
    const size_t offCursor = align256(offPairs + (size_t)NB * BCAP * 8);
    const size_t offSE     = align256(offCursor + (size_t)M * 4);
    const size_t need      = offSE + (size_t)N * 8;
    // Average load per shard-bucket must keep SCAP >= mean + ~10 sigma.
    const bool csr_ok = (need <= ws_size) && (N < (1 << 17)) &&
                        ((long long)E <= (long long)NB * (6 * SCAP));

    if (csr_ok) {
        unsigned short* Yb  = (unsigned short*)((char*)d_ws + offY);
        int2* pairs         = (int2*)((char*)d_ws + offPairs);
        int*  cursor        = (int*)((char*)d_ws + offCursor);
        int2* row_se        = (int2*)((char*)d_ws + offSE);

        gemm_mfma_kernel<<<(N + 63) / 64, 256, 0, stream>>>(x, W, b, Yb, N);
        init_cursor_kernel<<<(M + 255) / 256, 256, 0, stream>>>(cursor, M);
        bucket_scatter_kernel<<<NBLK, 256, 0, stream>>>(rows, cols, vals,
                                                        cursor, pairs, E);
        bucket_sort_kernel<<<NB, 256, 0, stream>>>(cursor, pairs, row_se, NB, N);
        gather_rows_kernel<<<(N + 3) / 4, 256, 0, stream>>>(
            pairs, row_se, (const unsigned int*)Yb, out, N);
    } else {
        float* Y = (float*)d_ws;
        hipMemsetAsync(d_out, 0, (size_t)out_size * sizeof(float), stream);
        gemm_bias_kernel<<<512, 256, 0, stream>>>(x, W, b, Y, N);
        scatter_kernel<<<(E + 3) / 4, 256, 0, stream>>>(rows, cols, vals, Y, out, E);
        elu_kernel<<<1024, 256, 0, stream>>>(out, out_size / 4);
    }
}

// Round 5
// 432.020 us; speedup vs baseline: 6.4385x; 1.0249x over previous
//
#include <hip/hip_runtime.h>
#include <hip/hip_bf16.h>
#include <cmath>

#define RPB  32          // rows per bucket
#define SCAP 240         // per-shard capacity per bucket (mean 128, +9.9 sigma)
#define BCAP (8 * SCAP)  // 1920: bucket slot capacity
#define NBLK 2048        // blocks for scatter pass (shard = blockIdx & 7)

typedef __attribute__((ext_vector_type(8))) short short8;
typedef __attribute__((ext_vector_type(4))) float floatx4;

__device__ __forceinline__ unsigned short f2bf(float f) {
    unsigned int u = __float_as_uint(f);
    u += 0x7FFFu + ((u >> 16) & 1u);   // RNE
    return (unsigned short)(u >> 16);
}
__device__ __forceinline__ int2 nt_load_int2(const int2* p) {
    const long long v = __builtin_nontemporal_load((const long long*)p);
    int2 r; r.x = (int)(unsigned int)v; r.y = (int)(v >> 32); return r;
}
__device__ __forceinline__ void nt_store_f2(float2 v, float* p) {
    __builtin_nontemporal_store(*(long long*)&v, (long long*)p);
}

// ---------------- MFMA GEMM: Yb[n][o] = bf16( x@W^T + b ) --------------------
__global__ __launch_bounds__(256) void gemm_mfma_kernel(
    const float* __restrict__ x, const float* __restrict__ W,
    const float* __restrict__ b, unsigned short* __restrict__ Yb, int N)
{
    __shared__ unsigned short Wb[128][136];
    __shared__ unsigned short Xb[64][136];
    const int t    = threadIdx.x;
    const int wave = t >> 6;
    const int lane = t & 63;
    const int col  = lane & 15;
    const int quad = lane >> 4;
    const int rowbase = blockIdx.x * 64;

#pragma unroll
    for (int i = 0; i < 16; ++i) {
        const int idx = t + 256 * i;
        const int o = idx >> 5, k4 = (idx & 31) * 4;
        const float4 v = *(const float4*)&W[(size_t)idx * 4];
        Wb[o][k4 + 0] = f2bf(v.x); Wb[o][k4 + 1] = f2bf(v.y);
        Wb[o][k4 + 2] = f2bf(v.z); Wb[o][k4 + 3] = f2bf(v.w);
    }
#pragma unroll
    for (int i = 0; i < 8; ++i) {
        const int idx = t + 256 * i;
        const int row = idx >> 5, k4 = (idx & 31) * 4;
        const int gr = rowbase + row;
        float4 v = make_float4(0.f, 0.f, 0.f, 0.f);
        if (gr < N) v = *(const float4*)&x[(size_t)gr * 128 + k4];
        Xb[row][k4 + 0] = f2bf(v.x); Xb[row][k4 + 1] = f2bf(v.y);
        Xb[row][k4 + 2] = f2bf(v.z); Xb[row][k4 + 3] = f2bf(v.w);
    }
    __syncthreads();

    float bias[8];
#pragma unroll
    for (int nt = 0; nt < 8; ++nt) bias[nt] = b[nt * 16 + col];

    floatx4 acc[8] = {};
    const int mrow = wave * 16;
#pragma unroll
    for (int k0 = 0; k0 < 128; k0 += 32) {
        const short8 a = *(const short8*)&Xb[mrow + col][k0 + quad * 8];
#pragma unroll
        for (int nt = 0; nt < 8; ++nt) {
            const short8 bf = *(const short8*)&Wb[nt * 16 + col][k0 + quad * 8];
            acc[nt] = __builtin_amdgcn_mfma_f32_16x16x32_bf16(a, bf, acc[nt], 0, 0, 0);
        }
    }
#pragma unroll
    for (int nt = 0; nt < 8; ++nt) {
#pragma unroll
        for (int reg = 0; reg < 4; ++reg) {
            const int gr = rowbase + mrow + quad * 4 + reg;
            if (gr < N)
                Yb[(size_t)gr * 128 + nt * 16 + col] = f2bf(acc[nt][reg] + bias[nt]);
        }
    }
}

// ---------------- P1: init bucket/shard cursors ------------------------------
__global__ __launch_bounds__(256) void init_cursor_kernel(int* __restrict__ cursor, int M)
{
    const int i = blockIdx.x * blockDim.x + threadIdx.x;
    if (i < M) cursor[i] = (i >> 3) * BCAP + (i & 7) * SCAP;
}

// ---------------- P2: append edges to bucket/shard streams -------------------
// nt loads: the 38.4 MB edge stream must NOT evict partial write lines in L2.
__global__ __launch_bounds__(256) void bucket_scatter_kernel(
    const int* __restrict__ rows, const int* __restrict__ cols,
    const float* __restrict__ vals, int* __restrict__ cursor,
    int2* __restrict__ pairs, int E)
{
    const int t = threadIdx.x;
    const int chunk = (E + NBLK - 1) / NBLK;
    const int lo = blockIdx.x * chunk;
    const int hi = min(lo + chunk, E);
    const int s = blockIdx.x & 7;
    for (int i = lo + t; i < hi; i += 256) {
        const int   r = __builtin_nontemporal_load(&rows[i]);
        const int   c = __builtin_nontemporal_load(&cols[i]);
        const float v = __builtin_nontemporal_load(&vals[i]);
        const int pos = atomicAdd(&cursor[(r >> 5) * 8 + s], 1);
        pairs[pos] = make_int2(((r & 31) << 17) | c, __float_as_int(v));
    }
}

// ---------------- P3: fused counting-sort (LDS) + gather + ELU ---------------
// One block per bucket of 32 rows. Sort ~1024 edges in LDS, then waves pull
// rows via a dynamic ticket and gather bf16 Y rows, fused ELU, nt stores.
__global__ __launch_bounds__(256) void sortgather_kernel(
    const int* __restrict__ cursor, const int2* __restrict__ pairs,
    const unsigned int* __restrict__ Yu, float* __restrict__ out, int N)
{
    __shared__ int2 sbuf[BCAP];
    __shared__ int2 dbuf[BCAP];
    __shared__ int hist[RPB];
    __shared__ int off[RPB];
    __shared__ int cur[RPB];
    __shared__ int segoff[9];
    __shared__ int rowtick;
    const int b    = blockIdx.x;
    const int t    = threadIdx.x;
    const int lane = t & 63;
    const int slot = b * BCAP;

    if (t < RPB) hist[t] = 0;
    if (t == 0) {
        rowtick = 0;
        int run = 0;
#pragma unroll
        for (int s = 0; s < 8; ++s) {
            segoff[s] = run;
            run += cursor[b * 8 + s] - (slot + s * SCAP);
        }
        segoff[8] = run;
    }
    __syncthreads();
    for (int s = 0; s < 8; ++s) {
        const int so = segoff[s];
        const int c  = segoff[s + 1] - so;
        for (int i = t; i < c; i += 256) {
            const int2 p = nt_load_int2(&pairs[slot + s * SCAP + i]);
            sbuf[so + i] = p;
            atomicAdd(&hist[p.x >> 17], 1);
        }
    }
    __syncthreads();
    if (t == 0) {
        int run = 0;
#pragma unroll
        for (int k = 0; k < RPB; ++k) { off[k] = run; cur[k] = run; run += hist[k]; }
    }
    __syncthreads();
    const int cnt = segoff[8];
    for (int i = t; i < cnt; i += 256) {
        const int2 p   = sbuf[i];
        const int  pos = atomicAdd(&cur[p.x >> 17], 1);
        dbuf[pos] = make_int2(p.x & 0x1FFFF, p.y);
    }
    __syncthreads();

    // Gather phase: dynamic row tickets per wave.
    for (;;) {
        int rl = 0;
        if (lane == 0) rl = atomicAdd(&rowtick, 1);
        rl = __shfl(rl, 0);
        if (rl >= RPB) break;
        const int gr = b * RPB + rl;
        if (gr >= N) continue;
        const int s = off[rl];
        const int e = s + hist[rl];

        float2 acc = make_float2(0.f, 0.f);
        int j = s;
        for (; j + 4 <= e; j += 4) {
            const int2 p0 = dbuf[j];
            const int2 p1 = dbuf[j + 1];
            const int2 p2 = dbuf[j + 2];
            const int2 p3 = dbuf[j + 3];
            const unsigned int y0 = Yu[(size_t)p0.x * 64 + lane];
            const unsigned int y1 = Yu[(size_t)p1.x * 64 + lane];
            const unsigned int y2 = Yu[(size_t)p2.x * 64 + lane];
            const unsigned int y3 = Yu[(size_t)p3.x * 64 + lane];
            acc.x = fmaf(__int_as_float(p0.y), __uint_as_float(y0 << 16), acc.x);
            acc.y = fmaf(__int_as_float(p0.y), __uint_as_float(y0 & 0xFFFF0000u), acc.y);
            acc.x = fmaf(__int_as_float(p1.y), __uint_as_float(y1 << 16), acc.x);
            acc.y = fmaf(__int_as_float(p1.y), __uint_as_float(y1 & 0xFFFF0000u), acc.y);
            acc.x = fmaf(__int_as_float(p2.y), __uint_as_float(y2 << 16), acc.x);
            acc.y = fmaf(__int_as_float(p2.y), __uint_as_float(y2 & 0xFFFF0000u), acc.y);
            acc.x = fmaf(__int_as_float(p3.y), __uint_as_float(y3 << 16), acc.x);
            acc.y = fmaf(__int_as_float(p3.y), __uint_as_float(y3 & 0xFFFF0000u), acc.y);
        }
        for (; j < e; ++j) {
            const int2 p = dbuf[j];
            const unsigned int y = Yu[(size_t)p.x * 64 + lane];
            acc.x = fmaf(__int_as_float(p.y), __uint_as_float(y << 16), acc.x);
            acc.y = fmaf(__int_as_float(p.y), __uint_as_float(y & 0xFFFF0000u), acc.y);
        }
        float2 o;
        o.x = acc.x > 0.f ? acc.x : expf(acc.x) - 1.f;
        o.y = acc.y > 0.f ? acc.y : expf(acc.y) - 1.f;
        nt_store_f2(o, &out[(size_t)gr * 128 + 2 * lane]);
    }
}

// ---------------- Fallback path (fp32, atomic scatter) -----------------------
__global__ __launch_bounds__(256) void gemm_bias_kernel(
    const float* __restrict__ x, const float* __restrict__ W,
    const float* __restrict__ b, float* __restrict__ Y, int N)
{
    __shared__ float Wt[128][130];
    const int tid  = threadIdx.x;
    const int wave = tid >> 6;
    const int lane = tid & 63;
    for (int i = tid; i < 128 * 128; i += 256) {
        const int o = i >> 7, k = i & 127;
        Wt[k][o] = W[i];
    }
    __syncthreads();
    const float2 bv = *(const float2*)&b[2 * lane];
    for (int row = blockIdx.x * 4 + wave; row < N; row += gridDim.x * 4) {
        float acc0 = 0.f, acc1 = 0.f;
        for (int k = 0; k < 128; ++k) {
            const float2 w = *(const float2*)&Wt[k][2 * lane];
            const float xv = x[(size_t)row * 128 + k];
            acc0 = fmaf(xv, w.x, acc0);
            acc1 = fmaf(xv, w.y, acc1);
        }
        float2 o2; o2.x = acc0 + bv.x; o2.y = acc1 + bv.y;
        *(float2*)&Y[(size_t)row * 128 + 2 * lane] = o2;
    }
}

__global__ __launch_bounds__(256) void scatter_kernel(
    const int* __restrict__ rows, const int* __restrict__ cols,
    const float* __restrict__ vals, const float* __restrict__ Y,
    float* __restrict__ out, int E)
{
    const long long gid = (long long)blockIdx.x * blockDim.x + threadIdx.x;
    const int wid  = (int)(gid >> 6);
    const int lane = threadIdx.x & 63;
    if (wid >= E) return;
    const int   r = rows[wid];
    const int   c = cols[wid];
    const float v = vals[wid];
    const float2 y = *(const float2*)&Y[(size_t)c * 128 + 2 * lane];
    float* po = &out[(size_t)r * 128 + 2 * lane];
    atomicAdd(po,     v * y.x);
    atomicAdd(po + 1, v * y.y);
}

__global__ __launch_bounds__(256) void elu_kernel(float* __restrict__ out, int n4)
{
    int i = blockIdx.x * blockDim.x + threadIdx.x;
    const int stride = gridDim.x * blockDim.x;
    float4* p = (float4*)out;
    for (; i < n4; i += stride) {
        float4 v = p[i];
        v.x = v.x > 0.f ? v.x : expf(v.x) - 1.f;
        v.y = v.y > 0.f ? v.y : expf(v.y) - 1.f;
        v.z = v.z > 0.f ? v.z : expf(v.z) - 1.f;
        v.w = v.w > 0.f ? v.w : expf(v.w) - 1.f;
        p[i] = v;
    }
}

// -----------------------------------------------------------------------------
extern "C" void kernel_launch(void* const* d_in, const int* in_sizes, int n_in,
                              void* d_out, int out_size, void* d_ws, size_t ws_size,
                              hipStream_t stream)
{
    const float* x    = (const float*)d_in[0];
    const float* W    = (const float*)d_in[1];
    const float* b    = (const float*)d_in[2];
    const int*   rows = (const int*)d_in[3];
    const int*   cols = (const int*)d_in[4];
    const float* vals = (const float*)d_in[5];
    float* out = (float*)d_out;

    const int N  = in_sizes[0] / 128;
    const int E  = in_sizes[3];
    const int NB = (N + RPB - 1) / RPB;
    const int M  = NB * 8;

    auto align256 = [](size_t v) { return (v + 255) & ~(size_t)255; };
    const size_t offY      = 0;                                   // bf16 Y
    const size_t offPairs  = align256(offY + (size_t)N * 128 * 2);
    const size_t offCursor = align256(offPairs + (size_t)NB * BCAP * 8);
    const size_t need      = offCursor + (size_t)M * 4;
    const bool csr_ok = (need <= ws_size) && (N < (1 << 17)) &&
                        ((long long)E <= (long long)NB * (6 * SCAP));

    if (csr_ok) {
        unsigned short* Yb = (unsigned short*)((char*)d_ws + offY);
        int2* pairs        = (int2*)((char*)d_ws + offPairs);
        int*  cursor       = (int*)((char*)d_ws + offCursor);

        gemm_mfma_kernel<<<(N + 63) / 64, 256, 0, stream>>>(x, W, b, Yb, N);
        init_cursor_kernel<<<(M + 255) / 256, 256, 0, stream>>>(cursor, M);
        bucket_scatter_kernel<<<NBLK, 256, 0, stream>>>(rows, cols, vals,
                                                        cursor, pairs, E);
        sortgather_kernel<<<NB, 256, 0, stream>>>(cursor, pairs,
                                                  (const unsigned int*)Yb, out, N);
    } else {
        float* Y = (float*)d_ws;
        hipMemsetAsync(d_out, 0, (size_t)out_size * sizeof(float), stream);
        gemm_bias_kernel<<<512, 256, 0, stream>>>(x, W, b, Y, N);
        scatter_kernel<<<(E + 3) / 4, 256, 0, stream>>>(rows, cols, vals, Y, out, E);
        elu_kernel<<<1024, 256, 0, stream>>>(out, out_size / 4);
    }
}

// Round 6
// 315.405 us; speedup vs baseline: 8.8190x; 1.3697x over previous
//
#include <hip/hip_runtime.h>
#include <hip/hip_bf16.h>
#include <cmath>

#define RPB      32        // rows per fine bucket
#define FB_CAP   1280      // fine-bucket slot capacity (mean 1024, +8 sigma)
#define SB_SHIFT 11        // 2048 rows per super-bucket
#define NSB_MAX  64
#define TILE     2048      // edges per binning tile
#define CH_PER_SB 34       // pass-2 chunks per super-bucket (cap/34 <= TILE)

typedef __attribute__((ext_vector_type(8))) short short8;
typedef __attribute__((ext_vector_type(4))) float floatx4;

__device__ __forceinline__ unsigned short f2bf(float f) {
    unsigned int u = __float_as_uint(f);
    u += 0x7FFFu + ((u >> 16) & 1u);   // RNE
    return (unsigned short)(u >> 16);
}

// ---------------- MFMA GEMM: Yb[n][o] = bf16( x@W^T + b ) --------------------
__global__ __launch_bounds__(256) void gemm_mfma_kernel(
    const float* __restrict__ x, const float* __restrict__ W,
    const float* __restrict__ b, unsigned short* __restrict__ Yb, int N)
{
    __shared__ unsigned short Wb[128][136];
    __shared__ unsigned short Xb[64][136];
    const int t    = threadIdx.x;
    const int wave = t >> 6;
    const int lane = t & 63;
    const int col  = lane & 15;
    const int quad = lane >> 4;
    const int rowbase = blockIdx.x * 64;

#pragma unroll
    for (int i = 0; i < 16; ++i) {
        const int idx = t + 256 * i;
        const int o = idx >> 5, k4 = (idx & 31) * 4;
        const float4 v = *(const float4*)&W[(size_t)idx * 4];
        Wb[o][k4 + 0] = f2bf(v.x); Wb[o][k4 + 1] = f2bf(v.y);
        Wb[o][k4 + 2] = f2bf(v.z); Wb[o][k4 + 3] = f2bf(v.w);
    }
#pragma unroll
    for (int i = 0; i < 8; ++i) {
        const int idx = t + 256 * i;
        const int row = idx >> 5, k4 = (idx & 31) * 4;
        const int gr = rowbase + row;
        float4 v = make_float4(0.f, 0.f, 0.f, 0.f);
        if (gr < N) v = *(const float4*)&x[(size_t)gr * 128 + k4];
        Xb[row][k4 + 0] = f2bf(v.x); Xb[row][k4 + 1] = f2bf(v.y);
        Xb[row][k4 + 2] = f2bf(v.z); Xb[row][k4 + 3] = f2bf(v.w);
    }
    __syncthreads();

    float bias[8];
#pragma unroll
    for (int nt = 0; nt < 8; ++nt) bias[nt] = b[nt * 16 + col];

    floatx4 acc[8] = {};
    const int mrow = wave * 16;
#pragma unroll
    for (int k0 = 0; k0 < 128; k0 += 32) {
        const short8 a = *(const short8*)&Xb[mrow + col][k0 + quad * 8];
#pragma unroll
        for (int nt = 0; nt < 8; ++nt) {
            const short8 bf = *(const short8*)&Wb[nt * 16 + col][k0 + quad * 8];
            acc[nt] = __builtin_amdgcn_mfma_f32_16x16x32_bf16(a, bf, acc[nt], 0, 0, 0);
        }
    }
#pragma unroll
    for (int nt = 0; nt < 8; ++nt) {
#pragma unroll
        for (int reg = 0; reg < 4; ++reg) {
            const int gr = rowbase + mrow + quad * 4 + reg;
            if (gr < N)
                Yb[(size_t)gr * 128 + nt * 16 + col] = f2bf(acc[nt][reg] + bias[nt]);
        }
    }
}

// ---------------- P0: init cursors -------------------------------------------
__global__ __launch_bounds__(256) void init_cursor_kernel(
    int* __restrict__ cursor1, int* __restrict__ cursor2, int SB_CAP, int NB)
{
    const int i = blockIdx.x * blockDim.x + threadIdx.x;
    if (i < NSB_MAX) cursor1[i] = i * SB_CAP;
    if (i < NB)      cursor2[i] = i * FB_CAP;
}

// ---------------- P1: tile sort by super-bucket, grouped writes --------------
// key layout in pairs1: .x = ((row & 2047) << 17) | col  (super-bucket implied
// by slot region), .y = val bits.
__global__ __launch_bounds__(256) void pass1_kernel(
    const int* __restrict__ rows, const int* __restrict__ cols,
    const float* __restrict__ vals, int* __restrict__ cursor1,
    int2* __restrict__ pairs1, int E)
{
    __shared__ int2 sbuf[TILE];
    __shared__ unsigned char sbin[TILE];
    __shared__ unsigned short perm[TILE];
    __shared__ int hist[NSB_MAX], off[NSB_MAX], gbase[NSB_MAX], cur[NSB_MAX];
    const int t  = threadIdx.x;
    const int lo = blockIdx.x * TILE;
    const int cnt = min(TILE, E - lo);

    if (t < NSB_MAX) hist[t] = 0;
    __syncthreads();
    for (int i = t; i < cnt; i += 256) {
        const int   r = rows[lo + i];
        const int   c = cols[lo + i];
        const float v = vals[lo + i];
        sbuf[i] = make_int2(((r & 2047) << 17) | c, __float_as_int(v));
        const int bb = r >> SB_SHIFT;
        sbin[i] = (unsigned char)bb;
        atomicAdd(&hist[bb], 1);
    }
    __syncthreads();
    if (t == 0) {
        int run = 0;
        for (int k = 0; k < NSB_MAX; ++k) { off[k] = run; cur[k] = run; run += hist[k]; }
    }
    __syncthreads();
    if (t < NSB_MAX && hist[t] > 0) gbase[t] = atomicAdd(&cursor1[t], hist[t]);
    __syncthreads();
    for (int i = t; i < cnt; i += 256) {
        const int pos = atomicAdd(&cur[sbin[i]], 1);
        perm[pos] = (unsigned short)i;
    }
    __syncthreads();
    for (int i = t; i < cnt; i += 256) {
        const int src = perm[i];
        const int bb  = sbin[src];
        pairs1[gbase[bb] + (i - off[bb])] = sbuf[src];
    }
}

// ---------------- P2: chunk sort by fine bucket, grouped writes --------------
__global__ __launch_bounds__(256) void pass2_kernel(
    const int* __restrict__ cursor1, int* __restrict__ cursor2,
    const int2* __restrict__ pairs1, int2* __restrict__ pairs2, int SB_CAP)
{
    __shared__ int2 sbuf[TILE];
    __shared__ unsigned short perm[TILE];
    __shared__ int hist[64], off[64], gbase[64], cur[64];
    const int t   = threadIdx.x;
    const int sb  = blockIdx.x / CH_PER_SB;
    const int ch  = blockIdx.x % CH_PER_SB;
    const int base = sb * SB_CAP;
    const int scnt = cursor1[sb] - base;
    const int csz  = (scnt + CH_PER_SB - 1) / CH_PER_SB;
    const int lo   = ch * csz;
    const int cnt  = max(0, min(csz, scnt - lo));

    if (t < 64) hist[t] = 0;
    __syncthreads();
    for (int i = t; i < cnt; i += 256) {
        const int2 p = pairs1[base + lo + i];
        sbuf[i] = p;
        atomicAdd(&hist[(unsigned)p.x >> 22], 1);   // fine bucket within sb
    }
    __syncthreads();
    if (t == 0) {
        int run = 0;
        for (int k = 0; k < 64; ++k) { off[k] = run; cur[k] = run; run += hist[k]; }
    }
    __syncthreads();
    if (t < 64 && hist[t] > 0)
        gbase[t] = atomicAdd(&cursor2[sb * 64 + t], hist[t]);
    __syncthreads();
    for (int i = t; i < cnt; i += 256) {
        const int pos = atomicAdd(&cur[(unsigned)sbuf[i].x >> 22], 1);
        perm[pos] = (unsigned short)i;
    }
    __syncthreads();
    for (int i = t; i < cnt; i += 256) {
        const int2 p = sbuf[perm[i]];
        const int bb = (unsigned)p.x >> 22;
        // keep ((row&31)<<17)|col for sortgather
        pairs2[gbase[bb] + (i - off[bb])] = make_int2(p.x & 0x3FFFFF, p.y);
    }
}

// ---------------- P3: fused counting-sort (LDS) + gather + ELU ---------------
__global__ __launch_bounds__(256) void sortgather_kernel(
    const int* __restrict__ cursor2, const int2* __restrict__ pairs2,
    const unsigned int* __restrict__ Yu, float* __restrict__ out, int N)
{
    __shared__ int2 sbuf[FB_CAP];
    __shared__ int2 dbuf[FB_CAP];
    __shared__ int hist[RPB];
    __shared__ int off[RPB];
    __shared__ int cur[RPB];
    __shared__ int rowtick;
    const int b    = blockIdx.x;
    const int t    = threadIdx.x;
    const int lane = t & 63;
    const int slot = b * FB_CAP;
    const int cnt  = cursor2[b] - slot;

    if (t < RPB) hist[t] = 0;
    if (t == 0) rowtick = 0;
    __syncthreads();
    for (int i = t; i < cnt; i += 256) {
        const int2 p = pairs2[slot + i];
        sbuf[i] = p;
        atomicAdd(&hist[p.x >> 17], 1);
    }
    __syncthreads();
    if (t == 0) {
        int run = 0;
#pragma unroll
        for (int k = 0; k < RPB; ++k) { off[k] = run; cur[k] = run; run += hist[k]; }
    }
    __syncthreads();
    for (int i = t; i < cnt; i += 256) {
        const int2 p   = sbuf[i];
        const int  pos = atomicAdd(&cur[p.x >> 17], 1);
        dbuf[pos] = make_int2(p.x & 0x1FFFF, p.y);
    }
    __syncthreads();

    for (;;) {
        int rl = 0;
        if (lane == 0) rl = atomicAdd(&rowtick, 1);
        rl = __shfl(rl, 0);
        if (rl >= RPB) break;
        const int gr = b * RPB + rl;
        if (gr >= N) continue;
        const int s = off[rl];
        const int e = s + hist[rl];

        float2 acc = make_float2(0.f, 0.f);
        int j = s;
        for (; j + 4 <= e; j += 4) {
            const int2 p0 = dbuf[j];
            const int2 p1 = dbuf[j + 1];
            const int2 p2 = dbuf[j + 2];
            const int2 p3 = dbuf[j + 3];
            const unsigned int y0 = Yu[(size_t)p0.x * 64 + lane];
            const unsigned int y1 = Yu[(size_t)p1.x * 64 + lane];
            const unsigned int y2 = Yu[(size_t)p2.x * 64 + lane];
            const unsigned int y3 = Yu[(size_t)p3.x * 64 + lane];
            acc.x = fmaf(__int_as_float(p0.y), __uint_as_float(y0 << 16), acc.x);
            acc.y = fmaf(__int_as_float(p0.y), __uint_as_float(y0 & 0xFFFF0000u), acc.y);
            acc.x = fmaf(__int_as_float(p1.y), __uint_as_float(y1 << 16), acc.x);
            acc.y = fmaf(__int_as_float(p1.y), __uint_as_float(y1 & 0xFFFF0000u), acc.y);
            acc.x = fmaf(__int_as_float(p2.y), __uint_as_float(y2 << 16), acc.x);
            acc.y = fmaf(__int_as_float(p2.y), __uint_as_float(y2 & 0xFFFF0000u), acc.y);
            acc.x = fmaf(__int_as_float(p3.y), __uint_as_float(y3 << 16), acc.x);
            acc.y = fmaf(__int_as_float(p3.y), __uint_as_float(y3 & 0xFFFF0000u), acc.y);
        }
        for (; j < e; ++j) {
            const int2 p = dbuf[j];
            const unsigned int y = Yu[(size_t)p.x * 64 + lane];
            acc.x = fmaf(__int_as_float(p.y), __uint_as_float(y << 16), acc.x);
            acc.y = fmaf(__int_as_float(p.y), __uint_as_float(y & 0xFFFF0000u), acc.y);
        }
        float2 o;
        o.x = acc.x > 0.f ? acc.x : expf(acc.x) - 1.f;
        o.y = acc.y > 0.f ? acc.y : expf(acc.y) - 1.f;
        *(float2*)&out[(size_t)gr * 128 + 2 * lane] = o;
    }
}

// ---------------- Fallback path (fp32, atomic scatter) -----------------------
__global__ __launch_bounds__(256) void gemm_bias_kernel(
    const float* __restrict__ x, const float* __restrict__ W,
    const float* __restrict__ b, float* __restrict__ Y, int N)
{
    __shared__ float Wt[128][130];
    const int tid  = threadIdx.x;
    const int wave = tid >> 6;
    const int lane = tid & 63;
    for (int i = tid; i < 128 * 128; i += 256) {
        const int o = i >> 7, k = i & 127;
        Wt[k][o] = W[i];
    }
    __syncthreads();
    const float2 bv = *(const float2*)&b[2 * lane];
    for (int row = blockIdx.x * 4 + wave; row < N; row += gridDim.x * 4) {
        float acc0 = 0.f, acc1 = 0.f;
        for (int k = 0; k < 128; ++k) {
            const float2 w = *(const float2*)&Wt[k][2 * lane];
            const float xv = x[(size_t)row * 128 + k];
            acc0 = fmaf(xv, w.x, acc0);
            acc1 = fmaf(xv, w.y, acc1);
        }
        float2 o2; o2.x = acc0 + bv.x; o2.y = acc1 + bv.y;
        *(float2*)&Y[(size_t)row * 128 + 2 * lane] = o2;
    }
}

__global__ __launch_bounds__(256) void scatter_kernel(
    const int* __restrict__ rows, const int* __restrict__ cols,
    const float* __restrict__ vals, const float* __restrict__ Y,
    float* __restrict__ out, int E)
{
    const long long gid = (long long)blockIdx.x * blockDim.x + threadIdx.x;
    const int wid  = (int)(gid >> 6);
    const int lane = threadIdx.x & 63;
    if (wid >= E) return;
    const int   r = rows[wid];
    const int   c = cols[wid];
    const float v = vals[wid];
    const float2 y = *(const float2*)&Y[(size_t)c * 128 + 2 * lane];
    float* po = &out[(size_t)r * 128 + 2 * lane];
    atomicAdd(po,     v * y.x);
    atomicAdd(po + 1, v * y.y);
}

__global__ __launch_bounds__(256) void elu_kernel(float* __restrict__ out, int n4)
{
    int i = blockIdx.x * blockDim.x + threadIdx.x;
    const int stride = gridDim.x * blockDim.x;
    float4* p = (float4*)out;
    for (; i < n4; i += stride) {
        float4 v = p[i];
        v.x = v.x > 0.f ? v.x : expf(v.x) - 1.f;
        v.y = v.y > 0.f ? v.y : expf(v.y) - 1.f;
        v.z = v.z > 0.f ? v.z : expf(v.z) - 1.f;
        v.w = v.w > 0.f ? v.w : expf(v.w) - 1.f;
        p[i] = v;
    }
}

// -----------------------------------------------------------------------------
extern "C" void kernel_launch(void* const* d_in, const int* in_sizes, int n_in,
                              void* d_out, int out_size, void* d_ws, size_t ws_size,
                              hipStream_t stream)
{
    const float* x    = (const float*)d_in[0];
    const float* W    = (const float*)d_in[1];
    const float* b    = (const float*)d_in[2];
    const int*   rows = (const int*)d_in[3];
    const int*   cols = (const int*)d_in[4];
    const float* vals = (const float*)d_in[5];
    float* out = (float*)d_out;

    const int N   = in_sizes[0] / 128;
    const int E   = in_sizes[3];
    const int NB  = (N + RPB - 1) / RPB;               // fine buckets
    const int NSB = (N + (1 << SB_SHIFT) - 1) >> SB_SHIFT;  // super-buckets

    // SB_CAP = mean + ~10 sigma, 64-aligned
    const int sb_mean = (E + NSB - 1) / NSB;
    int sbsig = 1; while (sbsig * sbsig < sb_mean) ++sbsig;
    const int SB_CAP = (sb_mean + 10 * sbsig + 63) & ~63;

    auto align256 = [](size_t v) { return (v + 255) & ~(size_t)255; };
    const size_t offPairs2 = 0;
    const size_t szPairs2  = (size_t)NB * FB_CAP * 8;
    const size_t offShared = align256(offPairs2 + szPairs2);   // pairs1 then Y
    const size_t szShared  = (size_t)NSB * SB_CAP * 8 > (size_t)N * 256
                           ? (size_t)NSB * SB_CAP * 8 : (size_t)N * 256;
    const size_t offCur1   = align256(offShared + szShared);
    const size_t offCur2   = align256(offCur1 + NSB_MAX * 4);
    const size_t need      = offCur2 + (size_t)NB * 4;

    const bool csr_ok = (need <= ws_size) && (NSB <= NSB_MAX) &&
                        ((long long)E <= (long long)NB * 1056) &&
                        (SB_CAP <= CH_PER_SB * TILE);

    if (csr_ok) {
        int2* pairs2        = (int2*)((char*)d_ws + offPairs2);
        int2* pairs1        = (int2*)((char*)d_ws + offShared);
        unsigned short* Yb  = (unsigned short*)((char*)d_ws + offShared);
        int*  cursor1       = (int*)((char*)d_ws + offCur1);
        int*  cursor2       = (int*)((char*)d_ws + offCur2);

        init_cursor_kernel<<<(NB + 255) / 256, 256, 0, stream>>>(cursor1, cursor2,
                                                                 SB_CAP, NB);
        pass1_kernel<<<(E + TILE - 1) / TILE, 256, 0, stream>>>(rows, cols, vals,
                                                                cursor1, pairs1, E);
        pass2_kernel<<<NSB * CH_PER_SB, 256, 0, stream>>>(cursor1, cursor2,
                                                          pairs1, pairs2, SB_CAP);
        // GEMM after pass2: Yb aliases pairs1 (dead now)
        gemm_mfma_kernel<<<(N + 63) / 64, 256, 0, stream>>>(x, W, b, Yb, N);
        sortgather_kernel<<<NB, 256, 0, stream>>>(cursor2, pairs2,
                                                  (const unsigned int*)Yb, out, N);
    } else {
        float* Y = (float*)d_ws;
        hipMemsetAsync(d_out, 0, (size_t)out_size * sizeof(float), stream);
        gemm_bias_kernel<<<512, 256, 0, stream>>>(x, W, b, Y, N);
        scatter_kernel<<<(E + 3) / 4, 256, 0, stream>>>(rows, cols, vals, Y, out, E);
        elu_kernel<<<1024, 256, 0, stream>>>(out, out_size / 4);
    }
}